// Round 8
// baseline (109.556 us; speedup 1.0000x reference)
//
#include <hip/hip_runtime.h>

typedef __fp16 f16x4 __attribute__((ext_vector_type(4)));
typedef __fp16 f16x2 __attribute__((ext_vector_type(2)));
typedef float f32x4 __attribute__((ext_vector_type(4)));

__device__ __forceinline__ f16x4 cat(f16x2 lo, f16x2 hi) {
    return __builtin_shufflevector(lo, hi, 0, 1, 2, 3);
}
__device__ __forceinline__ f16x2 u2h(unsigned v) {
    union { unsigned u; f16x2 h; } x; x.u = v; return x.h;
}
template <int CTRL>
__device__ __forceinline__ float dpp_add(float v) {
    int s = __builtin_amdgcn_update_dpp(0, __float_as_int(v), CTRL, 0xf, 0xf, true);
    return v + __int_as_float(s);
}

// DIAGNOSTIC ROUND: exact R7 algorithm executed TWICE per wave (opaque
// zero offset defeats CSE/DCE), so the kernel's duration (~2x) exceeds the
// harness's 41us poison-fill dispatches and lands in the rocprof top-5 with
// full counters. Output = 0.5*(r1+r2), bit-exact (passes are identical).
// R7 recap: one sample/wave, single coalesced float4 load; B-operand of x
// derived on-chip via D = x_A * I_B (C layout == B layout for 16x16x16f16);
// chain A_{s+1}=x*A_s repacked via pkrtz only; trace reduction via 2-MFMA
// passes; lane-parallel polynomial epilogue.
__global__ __launch_bounds__(256, 6) void acoef_kernel(
    const float* __restrict__ x,
    const float* __restrict__ coef,
    float* __restrict__ out)
{
    const int lane = threadIdx.x & 63;
    const int b = (blockIdx.x * 256 + (int)threadIdx.x) >> 6;

    const int n = lane & 15;
    const int q = lane >> 4;
    const bool diagsel = ((n >> 2) == q);

    // lane-constant fragments
    unsigned ilo = 0, ihi = 0;
    if (diagsel) {
        ilo = ((n & 3) == 0 ? 0x3C00u : 0u) | ((n & 3) == 1 ? 0x3C000000u : 0u);
        ihi = ((n & 3) == 2 ? 0x3C00u : 0u) | ((n & 3) == 3 ? 0x3C000000u : 0u);
    }
    const f16x4 idB = cat(u2h(ilo), u2h(ihi));
    unsigned slo = (n == 0 ? 0x3C00u : 0u) | (n == 1 ? 0x3C000000u : 0u);
    unsigned shi = (n == 2 ? 0x3C00u : 0u) | (n == 3 ? 0x3C000000u : 0u);
    const f16x4 selB  = cat(u2h(slo), u2h(shi));
    const f16x4 onesA = cat(u2h(0x3C003C00u), u2h(0x3C003C00u));
    const f32x4 zero  = {0.f, 0.f, 0.f, 0.f};

    float4 cf[3]; float scl[3];
    #pragma unroll
    for (int p = 0; p < 3; ++p) {
        int s = 4 * p + n;
        int idx = s > 9 ? 9 : s;
        cf[p]  = *(const float4*)(coef + 4 * idx);
        scl[p] = __int_as_float((127 - 8 * s) << 23);
    }

    float resacc = 0.0f;

    #pragma unroll 1
    for (int rep = 0; rep < 2; ++rep) {
        int zoff = 0;
        asm volatile("" : "+v"(zoff));   // opaque 0: blocks CSE/DCE across reps

        const float4 a = *(const float4*)(x + (size_t)b * 256 + n * 16 + 4 * q + zoff);

        f16x4 xA = cat(__builtin_amdgcn_cvt_pkrtz(a.x, a.y),
                       __builtin_amdgcn_cvt_pkrtz(a.z, a.w));
        f32x4 d = __builtin_amdgcn_mfma_f32_16x16x16f16(xA, idB, zero, 0, 0, 0);
        f16x4 xB = cat(__builtin_amdgcn_cvt_pkrtz(d[0], d[1]),
                       __builtin_amdgcn_cvt_pkrtz(d[2], d[3]));

        f32x4 acc = __builtin_amdgcn_mfma_f32_16x16x16f16(xA, xB, zero, 0, 0, 0);

        f16x2 prpk[6];
        float trf = 0.0f;
        #pragma unroll
        for (int st = 0; st < 10; ++st) {
            float sA = (n & 1) ? acc[1] : acc[0];
            float sB = (n & 1) ? acc[3] : acc[2];
            float dv = (n & 2) ? sB : sA;
            float tr = diagsel ? dv : 0.0f;
            if (st & 1) prpk[st >> 1] = __builtin_amdgcn_cvt_pkrtz(trf, tr);
            else        trf = tr;

            if (st < 9) {
                f16x4 bf = cat(__builtin_amdgcn_cvt_pkrtz(acc[0], acc[1]),
                               __builtin_amdgcn_cvt_pkrtz(acc[2], acc[3]));
                acc = __builtin_amdgcn_mfma_f32_16x16x16f16(xA, bf, zero, 0, 0, 0);
            }
        }
        prpk[5] = u2h(0u);

        float result = 0.0f;
        #pragma unroll
        for (int p = 0; p < 3; ++p) {
            f16x4 Ap = cat(prpk[2 * p], prpk[2 * p + 1]);
            f32x4 c1 = __builtin_amdgcn_mfma_f32_16x16x16f16(Ap, selB, zero, 0, 0, 0);
            f16x4 Bp = cat(__builtin_amdgcn_cvt_pkrtz(c1[0], c1[1]),
                           __builtin_amdgcn_cvt_pkrtz(c1[2], c1[3]));
            f32x4 c2 = __builtin_amdgcn_mfma_f32_16x16x16f16(onesA, Bp, zero, 0, 0, 0);
            float t = c2[0];
            float sv = t * 0x1p-8f;
            float h = fmaf(sv, cf[p].w, cf[p].z);
            h = fmaf(sv, h, cf[p].y);
            h = fmaf(sv, h, cf[p].x);
            result = fmaf(sv * h, scl[p], result);
        }
        result = dpp_add<0xB1>(result);
        result = dpp_add<0x4E>(result);
        resacc += result;
    }

    if (lane == 0) out[b] = 0.5f * resacc;   // r1 == r2 bit-exact -> = r1
}

extern "C" void kernel_launch(void* const* d_in, const int* in_sizes, int n_in,
                              void* d_out, int out_size, void* d_ws, size_t ws_size,
                              hipStream_t stream) {
    const float* x    = (const float*)d_in[0];   // [65536, 16, 16] fp32
    const float* coef = (const float*)d_in[1];   // [10, 4] fp32
    float* out        = (float*)d_out;           // [65536] fp32
    const int B = in_sizes[0] / 256;             // 65536 samples
    acoef_kernel<<<dim3(B / 4), dim3(256), 0, stream>>>(x, coef, out);
}

// Round 9
// 95.080 us; speedup vs baseline: 1.1523x; 1.1523x over previous
//
#include <hip/hip_runtime.h>

typedef __fp16 f16x4 __attribute__((ext_vector_type(4)));
typedef __fp16 f16x2 __attribute__((ext_vector_type(2)));
typedef float f32x4 __attribute__((ext_vector_type(4)));

__device__ __forceinline__ f16x4 cat(f16x2 lo, f16x2 hi) {
    return __builtin_shufflevector(lo, hi, 0, 1, 2, 3);
}
__device__ __forceinline__ f16x2 u2h(unsigned v) {
    union { unsigned u; f16x2 h; } x; x.u = v; return x.h;
}
template <int CTRL>
__device__ __forceinline__ float dpp_add(float v) {
    int s = __builtin_amdgcn_update_dpp(0, __float_as_int(v), CTRL, 0xf, 0xf, true);
    return v + __int_as_float(s);
}

// Persistent-wave software pipeline. R8's marginal-pass probe split R7's
// 28.8us into 12.4us warm compute + 16.4us cold-HBM convoy stall (waves in
// lockstep generations: burst-load -> stall -> compute -> repeat, memory and
// compute never overlapping). Fix: 6144 persistent waves (exactly 6
// blocks/CU), each streaming ~10.7 samples with a rotating one-float4
// register prefetch, so next-generation loads are in flight during current
// compute. Sample state is 4 regs thanks to the x*I B-derivation (R7), so
// (256,6)'s 85-VGPR cap holds without spills (R5's failure mode).
// Algorithm per sample (unchanged from R7): single coalesced float4 load;
// xB derived via D = x_A * I_B (C layout == B layout for 16x16x16f16);
// chain A_{s+1}=x*A_s repacked via pkrtz only; trace reduction via 2-MFMA
// passes; lane-parallel polynomial epilogue.
__global__ __launch_bounds__(256, 6) void acoef_kernel(
    const float* __restrict__ x,
    const float* __restrict__ coef,
    float* __restrict__ out,
    int B)
{
    const int lane = threadIdx.x & 63;
    const int wid  = (blockIdx.x * 256 + (int)threadIdx.x) >> 6;
    const int nw   = gridDim.x * 4;

    const int n = lane & 15;
    const int q = lane >> 4;
    const bool diagsel = ((n >> 2) == q);

    // lane-constant fragments
    unsigned ilo = 0, ihi = 0;
    if (diagsel) {
        ilo = ((n & 3) == 0 ? 0x3C00u : 0u) | ((n & 3) == 1 ? 0x3C000000u : 0u);
        ihi = ((n & 3) == 2 ? 0x3C00u : 0u) | ((n & 3) == 3 ? 0x3C000000u : 0u);
    }
    const f16x4 idB = cat(u2h(ilo), u2h(ihi));
    unsigned slo = (n == 0 ? 0x3C00u : 0u) | (n == 1 ? 0x3C000000u : 0u);
    unsigned shi = (n == 2 ? 0x3C00u : 0u) | (n == 3 ? 0x3C000000u : 0u);
    const f16x4 selB  = cat(u2h(slo), u2h(shi));
    const f16x4 onesA = cat(u2h(0x3C003C00u), u2h(0x3C003C00u));
    const f32x4 zero  = {0.f, 0.f, 0.f, 0.f};

    // per-lane coef rows + 256^{-s} scales (s = 4p + n; t=0 past row 9)
    float4 cf[3]; float scl[3];
    #pragma unroll
    for (int p = 0; p < 3; ++p) {
        int s = 4 * p + n;
        int idx = s > 9 ? 9 : s;
        cf[p]  = *(const float4*)(coef + 4 * idx);
        scl[p] = __int_as_float((127 - 8 * s) << 23);
    }

    const int laneoff = n * 16 + 4 * q;   // A: row n, cols 4q..4q+3

    int s = wid;
    float4 cur = *(const float4*)(x + (size_t)s * 256 + laneoff);

    #pragma unroll 1
    while (true) {
        const int s2 = s + nw;
        const bool more = (s2 < B);
        // prefetch next sample's fragment (clamped reload on the last iter)
        float4 nxt = *(const float4*)(x + (size_t)(more ? s2 : s) * 256 + laneoff);

        // ---- compute current sample ----
        f16x4 xA = cat(__builtin_amdgcn_cvt_pkrtz(cur.x, cur.y),
                       __builtin_amdgcn_cvt_pkrtz(cur.z, cur.w));
        f32x4 d = __builtin_amdgcn_mfma_f32_16x16x16f16(xA, idB, zero, 0, 0, 0);
        f16x4 xB = cat(__builtin_amdgcn_cvt_pkrtz(d[0], d[1]),
                       __builtin_amdgcn_cvt_pkrtz(d[2], d[3]));

        f32x4 acc = __builtin_amdgcn_mfma_f32_16x16x16f16(xA, xB, zero, 0, 0, 0);

        f16x2 prpk[6];
        float trf = 0.0f;
        #pragma unroll
        for (int st = 0; st < 10; ++st) {
            float sA = (n & 1) ? acc[1] : acc[0];
            float sB = (n & 1) ? acc[3] : acc[2];
            float dv = (n & 2) ? sB : sA;
            float tr = diagsel ? dv : 0.0f;
            if (st & 1) prpk[st >> 1] = __builtin_amdgcn_cvt_pkrtz(trf, tr);
            else        trf = tr;

            if (st < 9) {
                f16x4 bf = cat(__builtin_amdgcn_cvt_pkrtz(acc[0], acc[1]),
                               __builtin_amdgcn_cvt_pkrtz(acc[2], acc[3]));
                acc = __builtin_amdgcn_mfma_f32_16x16x16f16(xA, bf, zero, 0, 0, 0);
            }
        }
        prpk[5] = u2h(0u);

        float result = 0.0f;
        #pragma unroll
        for (int p = 0; p < 3; ++p) {
            f16x4 Ap = cat(prpk[2 * p], prpk[2 * p + 1]);
            f32x4 c1 = __builtin_amdgcn_mfma_f32_16x16x16f16(Ap, selB, zero, 0, 0, 0);
            f16x4 Bp = cat(__builtin_amdgcn_cvt_pkrtz(c1[0], c1[1]),
                           __builtin_amdgcn_cvt_pkrtz(c1[2], c1[3]));
            f32x4 c2 = __builtin_amdgcn_mfma_f32_16x16x16f16(onesA, Bp, zero, 0, 0, 0);
            float t = c2[0];
            float sv = t * 0x1p-8f;
            float h = fmaf(sv, cf[p].w, cf[p].z);
            h = fmaf(sv, h, cf[p].y);
            h = fmaf(sv, h, cf[p].x);
            result = fmaf(sv * h, scl[p], result);
        }
        result = dpp_add<0xB1>(result);
        result = dpp_add<0x4E>(result);
        if (lane == 0) out[s] = result;

        if (!more) break;
        s = s2; cur = nxt;
    }
}

extern "C" void kernel_launch(void* const* d_in, const int* in_sizes, int n_in,
                              void* d_out, int out_size, void* d_ws, size_t ws_size,
                              hipStream_t stream) {
    const float* x    = (const float*)d_in[0];   // [65536, 16, 16] fp32
    const float* coef = (const float*)d_in[1];   // [10, 4] fp32
    float* out        = (float*)d_out;           // [65536] fp32
    const int B = in_sizes[0] / 256;             // 65536 samples
    // 1536 blocks = exactly 6 blocks/CU resident (one generation), 6144 waves
    acoef_kernel<<<dim3(1536), dim3(256), 0, stream>>>(x, coef, out, B);
}